// Round 9
// baseline (1109.807 us; speedup 1.0000x reference)
//
#include <hip/hip_runtime.h>

#define NN   16384
#define NE   262144
#define NB   32
#define H    128
#define NH   (NN*H)
#define RBF  50
#define TM   64
#define KC   64
#define KP   72     // node-kernel LDS staging pitch (u16)
#define HBP  136    // wave-buffer pitch (u16): 272 B rows
#define CHW  9216   // edge weight chunk: [128 rows][72 u16] (64 k + 8 pad)
#define LT2  115712 // packed edge weights per layer: 9*9216 + 16384(m1d) + 16384(m1s)
#define LN_  49152  // packed node weights per layer (u16)
#define NG   196608 // offset of global node weights in packn

typedef unsigned short u16;
typedef short bf16x8 __attribute__((ext_vector_type(8)));
typedef float f32x4 __attribute__((ext_vector_type(4)));

#if defined(__has_builtin)
#if __has_builtin(__builtin_amdgcn_cvt_pk_bf16_f32)
#define HAS_PK_BF16 1
#endif
#endif

__device__ __forceinline__ float sigmoidf_(float v){ return 1.0f/(1.0f + __expf(-v)); }
__device__ __forceinline__ float siluf_(float v){ return v * sigmoidf_(v); }
__device__ __forceinline__ u16 f2bf(float f){
  unsigned u = __float_as_uint(f);
  return (u16)((u + 0x7FFFu + ((u>>16)&1u)) >> 16);
}
__device__ __forceinline__ float bf2f(u16 v){ return __uint_as_float(((unsigned)v)<<16); }
// 2×f32 -> packed bf16x2 in one VALU op on gfx950 (RNE, matches f2bf)
__device__ __forceinline__ unsigned pk2(float a, float b){
#ifdef HAS_PK_BF16
  typedef __bf16 v2bf __attribute__((ext_vector_type(2)));
  v2bf v = __builtin_amdgcn_cvt_pk_bf16_f32(a, b);
  return __builtin_bit_cast(unsigned, v);
#else
  return (unsigned)f2bf(a) | ((unsigned)f2bf(b)<<16);
#endif
}
__device__ __forceinline__ uint2 pack4(float a, float b, float c, float d){
  uint2 r; r.x = pk2(a,b); r.y = pk2(c,d); return r;
}
__device__ __forceinline__ float blo(unsigned u){ return bf2f((u16)(u & 0xffffu)); }
__device__ __forceinline__ float bhi(unsigned u){ return bf2f((u16)(u >> 16)); }

template<int ACT>
__device__ __forceinline__ float apply_act(float v){ return (ACT==1) ? siluf_(v) : v; }

// ---- node-kernel LDS staging macros (proven R6/R8) ----
#define STAGE_WT(GSRC, KPAD, K0) \
  _Pragma("unroll") \
  for (int i_=0;i_<4;i_++){ \
    int o_ = tid + i_*256; \
    int c_ = o_ >> 3, ko_ = (o_ & 7)*8; \
    *(uint4*)&Wt[c_][ko_] = *(const uint4*)((GSRC) + (size_t)c_*(KPAD) + (K0) + ko_); \
  }

#define STAGE_AB(ROWPTR) \
  _Pragma("unroll") \
  for (int i_=0;i_<2;i_++){ \
    int o_ = tid*2 + i_; \
    int r_ = o_ >> 3, ko_ = (o_ & 7)*8; \
    const u16* rp_ = (ROWPTR); \
    *(uint4*)&Ab[r_][ko_] = *(const uint4*)(rp_ + ko_); \
  }

#define STAGE_AF(FROWPTR) \
  _Pragma("unroll") \
  for (int i_=0;i_<2;i_++){ \
    int o_ = tid*2 + i_; \
    int r_ = o_ >> 3, ko_ = (o_ & 7)*8; \
    const float* rp_ = (FROWPTR); \
    float4 f0_ = *(const float4*)(rp_ + ko_); \
    float4 f1_ = *(const float4*)(rp_ + ko_ + 4); \
    uint4 pk_; \
    pk_.x = pk2(f0_.x, f0_.y); pk_.y = pk2(f0_.z, f0_.w); \
    pk_.z = pk2(f1_.x, f1_.y); pk_.w = pk2(f1_.z, f1_.w); \
    *(uint4*)&Ab[r_][ko_] = pk_; \
  }

#define MFMA_TILES(BBUF, KOFF, ACC) \
  _Pragma("unroll") \
  for (int ks_=0; ks_<KC; ks_+=32){ \
    bf16x8 bf_ = *(const bf16x8*)&BBUF[wrow + l15][(KOFF) + ks_ + q8]; \
    _Pragma("unroll") \
    for (int t_=0;t_<8;t_++){ \
      bf16x8 wf_ = *(const bf16x8*)&Wt[t_*16 + l15][ks_ + q8]; \
      ACC[t_] = __builtin_amdgcn_mfma_f32_16x16x32_bf16(wf_, bf_, ACC[t_], 0, 0, 0); \
    } \
  }

// ---- edge-kernel chunk MFMA: weights in flat WT[9216], B from wave-local buf ----
#define ECHUNK(BUF, OFF, ACC) { \
  bf16x8 b0_ = *(const bf16x8*)&BUF[l15][(OFF) + q8]; \
  bf16x8 b1_ = *(const bf16x8*)&BUF[l15][(OFF) + 32 + q8]; \
  _Pragma("unroll") \
  for (int t_=0;t_<8;t_++){ \
    bf16x8 w0_ = *(const bf16x8*)&WT[(t_*16+l15)*72 + q8]; \
    ACC[t_] = __builtin_amdgcn_mfma_f32_16x16x32_bf16(w0_, b0_, ACC[t_], 0, 0, 0); \
  } \
  _Pragma("unroll") \
  for (int t_=0;t_<8;t_++){ \
    bf16x8 w1_ = *(const bf16x8*)&WT[(t_*16+l15)*72 + 32 + q8]; \
    ACC[t_] = __builtin_amdgcn_mfma_f32_16x16x32_bf16(w1_, b1_, ACC[t_], 0, 0, 0); \
  } }

#define ECHUNK_RB(B0, B1, ACC) { \
  _Pragma("unroll") \
  for (int t_=0;t_<8;t_++){ \
    bf16x8 w0_ = *(const bf16x8*)&WT[(t_*16+l15)*72 + q8]; \
    ACC[t_] = __builtin_amdgcn_mfma_f32_16x16x32_bf16(w0_, B0, ACC[t_], 0, 0, 0); \
  } \
  _Pragma("unroll") \
  for (int t_=0;t_<8;t_++){ \
    bf16x8 w1_ = *(const bf16x8*)&WT[(t_*16+l15)*72 + 32 + q8]; \
    ACC[t_] = __builtin_amdgcn_mfma_f32_16x16x32_bf16(w1_, B1, ACC[t_], 0, 0, 0); \
  } }

// register-prefetch staging of one 18432B chunk (1152 uint4 slots, 256 threads)
#define LOADW(c) { \
  const uint4* gs_ = (const uint4*)(pw + (size_t)(c)*CHW); \
  p0 = gs_[tid]; p1 = gs_[tid+256]; p2 = gs_[tid+512]; p3 = gs_[tid+768]; \
  if (tid < 128) p4 = gs_[tid+1024]; }
#define STOREW() { \
  uint4* wd_ = (uint4*)WT; \
  wd_[tid] = p0; wd_[tid+256] = p1; wd_[tid+512] = p2; wd_[tid+768] = p3; \
  if (tid < 128) wd_[tid+1024] = p4; }

// ---------------------------------------------------------------- utility
__global__ void k_zero(float* __restrict__ p, int n){
  int i = blockIdx.x*256 + threadIdx.x; if (i < n) p[i] = 0.f;
}
__global__ void k_zero_i(int* __restrict__ p, int n){
  int i = blockIdx.x*256 + threadIdx.x; if (i < n) p[i] = 0;
}
__global__ void k_embed(const int* __restrict__ z, const float* __restrict__ emb,
                        float* __restrict__ x, u16* __restrict__ xb){
  int i = blockIdx.x*256 + threadIdx.x;
  int n = i >> 7, h = i & 127;
  float v = emb[z[n]*H + h];
  x[i] = v; xb[i] = f2bf(v);
}
__global__ void k_af(float* __restrict__ io, u16* __restrict__ ob){
  int i = blockIdx.x*256 + threadIdx.x;
  float v = io[i]*(1.0f/3.0f);
  io[i] = v; ob[i] = f2bf(v);
}

// ---------------------------------------------------------------- weight packing
// Edge layout per layer: chunks c=0..8 of [128][72] (64 valid k):
// 0:ee1 1,2:ee2 3,4:m1e 5,6:gate 7,8:msg2 ; then m1d dense @82944, m1s dense @99328.
__global__ void k_pack(const float* __restrict__ ee_w1, const float* __restrict__ ee_w2,
                       const float* __restrict__ msg_w1, const float* __restrict__ msg_w2,
                       const float* __restrict__ gate_w, u16* __restrict__ out){
  int idx = blockIdx.x*256 + threadIdx.x;
  int l = blockIdx.y;
  if (idx >= LT2) return;
  u16* o = out + (size_t)l*LT2;
  float v = 0.f;
  if (idx < 82944){
    int c = idx / CHW, r = idx % CHW, row = r / 72, col = r % 72;
    if (col < 64){
      if (c == 0)      v = (col < RBF) ? ee_w1[(size_t)l*RBF*H + col*H + row] : 0.f;
      else if (c <= 2) v = ee_w2 [(size_t)l*H*H + (64*(c-1)+col)*H + row];
      else if (c <= 4) v = msg_w1[(size_t)l*3*H*H + (256 + 64*(c-3)+col)*H + row];
      else if (c <= 6) v = gate_w[(size_t)l*H*H + (64*(c-5)+col)*H + row];
      else             v = msg_w2[(size_t)l*H*H + (64*(c-7)+col)*H + row];
    }
  } else if (idx < 99328){
    int j = idx - 82944; int row = j >> 7, k = j & 127;
    v = msg_w1[(size_t)l*3*H*H + k*H + row];
  } else {
    int j = idx - 99328; int row = j >> 7, k = j & 127;
    v = msg_w1[(size_t)l*3*H*H + (128+k)*H + row];
  }
  o[idx] = f2bf(v);
}

__global__ void k_packn(const float* __restrict__ upd_w1, const float* __restrict__ upd_w2,
                        const float* __restrict__ ro_w1, const float* __restrict__ ro_w2,
                        const float* __restrict__ pn_w, const float* __restrict__ gp_w1,
                        u16* __restrict__ out){
  int idx = blockIdx.x*256 + threadIdx.x;
  if (idx >= NG + 65536) return;
  float v;
  if (idx < NG){
    int l = idx / LN_, j = idx % LN_;
    if (j < 32768){ int c = j>>8, k = j&255; v = upd_w1[(size_t)l*256*H + k*H + c]; }
    else { int j2 = j-32768; int c = j2>>7, k = j2&127; v = upd_w2[(size_t)l*H*H + k*H + c]; }
  } else {
    int j = idx - NG; int m = j >> 14; int j2 = j & 16383;
    int c = j2>>7, k = j2&127;
    const float* W = (m==0) ? ro_w1 : (m==1) ? ro_w2 : (m==2) ? pn_w : gp_w1;
    v = W[k*H + c];
  }
  out[idx] = f2bf(v);
}

// ---------------------------------------------------------------- edge sort by dst
__global__ void k_hist(const int* __restrict__ dstv, int* __restrict__ cnt){
  int e = blockIdx.x*256 + threadIdx.x;
  if (e < NE) atomicAdd(&cnt[dstv[e]], 1);
}
__global__ __launch_bounds__(1024)
void k_scan(int* __restrict__ cnt, int* __restrict__ start){
  __shared__ int ps[1024];
  int tid = threadIdx.x;
  int base = tid*16;
  int loc[16]; int s = 0;
#pragma unroll
  for (int i=0;i<16;i++){ loc[i] = s; s += cnt[base+i]; }
  ps[tid] = s; __syncthreads();
  for (int off=1; off<1024; off<<=1){
    int v = (tid>=off) ? ps[tid-off] : 0;
    __syncthreads();
    ps[tid] += v;
    __syncthreads();
  }
  int pre = (tid>0) ? ps[tid-1] : 0;
#pragma unroll
  for (int i=0;i<16;i++){ int v = pre + loc[i]; start[base+i] = v; cnt[base+i] = v; }
  if (tid == 0) start[NN] = NE;
}
__global__ void k_scatter(const int* __restrict__ srcv, const int* __restrict__ dstv,
                          int* __restrict__ cursor, int* __restrict__ src_s,
                          int* __restrict__ dst_s){
  int e = blockIdx.x*256 + threadIdx.x;
  if (e >= NE) return;
  int d = dstv[e];
  int p = atomicAdd(&cursor[d], 1);
  src_s[p] = srcv[e]; dst_s[p] = d;
}

// ---------------------------------------------------------------- FUSED edge pipeline
// LDS-staged weights (register-prefetch), ONE wave-private data buffer (gate
// reordered before msg-hidden overwrite), hoisted msg1 x-parts via prefetched regs.
__global__ __launch_bounds__(256)
void k_edge(const int* __restrict__ src_s, const int* __restrict__ dst_s,
            const float* __restrict__ pos, const float* __restrict__ widths,
            const u16* __restrict__ y1b, const u16* __restrict__ y2b,
            const u16* __restrict__ pw,
            const float* __restrict__ b_ee1, const float* __restrict__ b_ee2,
            const float* __restrict__ b_m2, const float* __restrict__ b_g,
            float* __restrict__ aggr){
  __shared__ u16 WT[CHW];            // 18.4 KB weight chunk
  __shared__ u16 SB[4][16][HBP];     // 17.4 KB wave-local (total 35.8 KB -> 4 blocks/CU)
  const int tid = threadIdx.x;
  const int wave = tid>>6, l = tid&63, l15 = l&15, quad = l>>4, q8 = quad*8;
  const int ebase = blockIdx.x*TM + wave*16;
  const int eid   = ebase + l15;
  u16 (*Sb)[HBP] = SB[wave];

  // ---- per-lane edge geometry + RBF fragments (registers)
  const int esrc = src_s[eid], edst = dst_s[eid];
  float dx = pos[3*edst]   - pos[3*esrc];
  float dy = pos[3*edst+1] - pos[3*esrc+1];
  float dz = pos[3*edst+2] - pos[3*esrc+2];
  float dist = sqrtf(dx*dx + dy*dy + dz*dz);
  float cut  = (dist < 5.0f) ? 0.5f*(__cosf(0.62831853f*dist) + 1.0f) : 0.0f;
  bf16x8 rb0, rb1;
#pragma unroll
  for (int j=0;j<8;j++){
    int k0 = q8 + j, k1 = 32 + q8 + j;
    float t0 = dist - 0.10204082f*(float)k0;
    float t1 = dist - 0.10204082f*(float)k1;
    float w0 = widths[k0 < RBF ? k0 : 0], w1 = widths[k1 < RBF ? k1 : 0];
    float v0 = (k0 < RBF) ? __expf(-(1.0f/(2.0f*w0*w0))*t0*t0)*cut : 0.f;
    float v1 = (k1 < RBF) ? __expf(-(1.0f/(2.0f*w1*w1))*t1*t1)*cut : 0.f;
    ((u16*)&rb0)[j] = f2bf(v0);
    ((u16*)&rb1)[j] = f2bf(v1);
  }

  // ---- prefetch y1[dst], y2[src] gathers (hidden behind ee+gate phases)
  uint2 gy1[8], gy2[8];
#pragma unroll
  for (int t=0;t<8;t++){
    int co = t*16 + quad*4;
    gy1[t] = *(const uint2*)&y1b[(size_t)edst*H + co];
    gy2[t] = *(const uint2*)&y2b[(size_t)esrc*H + co];
  }

  uint4 p0, p1, p2, p3, p4;
  LOADW(0) STOREW() LOADW(1)
  __syncthreads();                       // chunk0 (ee1) ready

  f32x4 acc[8], accG[8];
#pragma unroll
  for (int t=0;t<8;t++) acc[t] = (f32x4)(0.f);
  ECHUNK_RB(rb0, rb1, acc)               // ee1 (K=64)
#pragma unroll
  for (int t=0;t<8;t++){                 // hidden silu -> Sb
    int co = t*16 + quad*4;
    float4 b = *(const float4*)(b_ee1 + co);
    *(uint2*)&Sb[l15][co] = pack4(
      siluf_(acc[t][0]+b.x), siluf_(acc[t][1]+b.y),
      siluf_(acc[t][2]+b.z), siluf_(acc[t][3]+b.w));
  }
  __syncthreads(); STOREW(); __syncthreads(); LOADW(2)
#pragma unroll
  for (int t=0;t<8;t++) acc[t] = (f32x4)(0.f);
  ECHUNK(Sb, 0, acc)                     // ee2 k0-63
  __syncthreads(); STOREW(); __syncthreads(); LOADW(3)
  ECHUNK(Sb, 64, acc)                    // ee2 k64-127
#pragma unroll
  for (int t=0;t<8;t++){                 // ee -> Sb (hidden fully consumed)
    int co = t*16 + quad*4;
    float4 b = *(const float4*)(b_ee2 + co);
    *(uint2*)&Sb[l15][co] = pack4(
      acc[t][0]+b.x, acc[t][1]+b.y, acc[t][2]+b.z, acc[t][3]+b.w);
  }
  __syncthreads(); STOREW(); __syncthreads(); LOADW(4)
#pragma unroll
  for (int t=0;t<8;t++) acc[t] = (f32x4)(0.f);
  ECHUNK(Sb, 0, acc)                     // m1e k0-63 (reads ee)
  __syncthreads(); STOREW(); __syncthreads(); LOADW(5)
  ECHUNK(Sb, 64, acc)                    // m1e k64-127
  __syncthreads(); STOREW(); __syncthreads(); LOADW(6)
#pragma unroll
  for (int t=0;t<8;t++) accG[t] = (f32x4)(0.f);
  ECHUNK(Sb, 0, accG)                    // gate k0-63 (reads ee)
  __syncthreads(); STOREW(); __syncthreads(); LOADW(7)
  ECHUNK(Sb, 64, accG)                   // gate k64-127 (ee fully consumed)
#pragma unroll
  for (int t=0;t<8;t++){                 // msg hidden: + y1[dst] + y2[src], silu -> Sb
    int co = t*16 + quad*4;
    float v0 = acc[t][0] + blo(gy1[t].x) + blo(gy2[t].x);
    float v1 = acc[t][1] + bhi(gy1[t].x) + bhi(gy2[t].x);
    float v2 = acc[t][2] + blo(gy1[t].y) + blo(gy2[t].y);
    float v3 = acc[t][3] + bhi(gy1[t].y) + bhi(gy2[t].y);
    *(uint2*)&Sb[l15][co] = pack4(siluf_(v0), siluf_(v1), siluf_(v2), siluf_(v3));
  }
  __syncthreads(); STOREW(); __syncthreads(); LOADW(8)
#pragma unroll
  for (int t=0;t<8;t++) acc[t] = (f32x4)(0.f);
  ECHUNK(Sb, 0, acc)                     // msg2 k0-63
  __syncthreads(); STOREW(); __syncthreads();
  ECHUNK(Sb, 64, acc)                    // msg2 k64-127
#pragma unroll
  for (int t=0;t<8;t++){                 // gated message -> Sb
    int co = t*16 + quad*4;
    float4 bm = *(const float4*)(b_m2 + co);
    float4 bg = *(const float4*)(b_g + co);
    float m0 = acc[t][0]+bm.x, m1 = acc[t][1]+bm.y;
    float m2 = acc[t][2]+bm.z, m3 = acc[t][3]+bm.w;
    float g0 = sigmoidf_(accG[t][0]+bg.x), g1 = sigmoidf_(accG[t][1]+bg.y);
    float g2 = sigmoidf_(accG[t][2]+bg.z), g3 = sigmoidf_(accG[t][3]+bg.w);
    *(uint2*)&Sb[l15][co] = pack4(m0*g0, m1*g1, m2*g2, m3*g3);
  }

  // ---- wave-local segmented reduce (dst-sorted): 2 cols per lane over 16 rows
  {
    int c0 = l*2;
    float a0 = 0.f, a1 = 0.f;
    int cur = dst_s[ebase];
#pragma unroll
    for (int r=0; r<16; r++){
      int d = dst_s[ebase + r];
      if (d != cur){
        atomicAdd(&aggr[(size_t)cur*H + c0],     a0);
        atomicAdd(&aggr[(size_t)cur*H + c0 + 1], a1);
        a0 = 0.f; a1 = 0.f; cur = d;
      }
      unsigned pv = *(const unsigned*)&Sb[r][c0];
      a0 += blo(pv); a1 += bhi(pv);
    }
    atomicAdd(&aggr[(size_t)cur*H + c0],     a0);
    atomicAdd(&aggr[(size_t)cur*H + c0 + 1], a1);
  }
}

// ---------------------------------------------------------------- node MFMA kernels
// fused y1 = x@W1d + b_m1 ; y2 = x@W1s  (one pass over xb)
__global__ __launch_bounds__(256)
void k_y12(const u16* __restrict__ xb, const u16* __restrict__ Wd,
           const u16* __restrict__ Ws, const float* __restrict__ b1,
           u16* __restrict__ y1, u16* __restrict__ y2){
  __shared__ u16 Ab[TM][KP];
  __shared__ u16 Wt[H][KP];
  __shared__ float bls[H];
  const int tid = threadIdx.x;
  const int wave = tid>>6, l = tid&63, l15 = l&15, quad = l>>4;
  const int wrow = wave*16, q8 = quad*8;
  const int rowbase = blockIdx.x*TM;
  if (tid < H) bls[tid] = b1[tid];
  f32x4 a1[8], a2[8];
#pragma unroll
  for (int t=0;t<8;t++){ a1[t] = (f32x4)(0.f); a2[t] = (f32x4)(0.f); }
  for (int kc=0; kc<H; kc+=KC){
    __syncthreads();
    STAGE_AB(xb + (size_t)(rowbase + r_)*H + kc)
    STAGE_WT(Wd, 128, kc)
    __syncthreads();
    MFMA_TILES(Ab, 0, a1)
    __syncthreads();
    STAGE_WT(Ws, 128, kc)
    __syncthreads();
    MFMA_TILES(Ab, 0, a2)
  }
  const int node = rowbase + wrow + l15;
#pragma unroll
  for (int t=0;t<8;t++){
    int co = t*16 + quad*4;
    *(uint2*)&y1[(size_t)node*H + co] = pack4(
      a1[t][0]+bls[co], a1[t][1]+bls[co+1], a1[t][2]+bls[co+2], a1[t][3]+bls[co+3]);
    *(uint2*)&y2[(size_t)node*H + co] = pack4(
      a2[t][0], a2[t][1], a2[t][2], a2[t][3]);
  }
}

// upd1: concat(aggr f32, xb bf16) @ W (K=256) + b, silu -> bf16 ; re-zeros aggr rows
__global__ __launch_bounds__(256)
void k_upd1(float* __restrict__ aggr, const u16* __restrict__ xb,
            const u16* __restrict__ Wp, const float* __restrict__ bias,
            u16* __restrict__ outb){
  __shared__ u16 Ab[TM][KP];
  __shared__ u16 Wt[H][KP];
  __shared__ float bls[H];
  const int tid = threadIdx.x;
  const int wave = tid>>6, l = tid&63, l15 = l&15, quad = l>>4;
  const int wrow = wave*16, q8 = quad*8;
  const int rowbase = blockIdx.x*TM;
  if (tid < H) bls[tid] = bias[tid];
  f32x4 acc[8];
#pragma unroll
  for (int t=0;t<8;t++) acc[t] = (f32x4)(0.f);
  for (int kc=0; kc<256; kc+=KC){
    __syncthreads();
    if (kc < 128) { STAGE_AF(aggr + (size_t)(rowbase + r_)*H + kc) }
    else          { STAGE_AB(xb + (size_t)(rowbase + r_)*H + (kc-128)) }
    STAGE_WT(Wp, 256, kc)
    __syncthreads();
    MFMA_TILES(Ab, 0, acc)
  }
  // re-zero this block's aggr rows for the next layer (all reads done above)
  {
    float4 z = make_float4(0.f,0.f,0.f,0.f);
#pragma unroll
    for (int i=0;i<8;i++){
      int o = tid + i*256;
      *(float4*)&aggr[(size_t)rowbase*H + (size_t)o*4] = z;
    }
  }
  const int node = rowbase + wrow + l15;
#pragma unroll
  for (int t=0;t<8;t++){
    int co = t*16 + quad*4;
    *(uint2*)&outb[(size_t)node*H + co] = pack4(
      siluf_(acc[t][0]+bls[co]),   siluf_(acc[t][1]+bls[co+1]),
      siluf_(acc[t][2]+bls[co+2]), siluf_(acc[t][3]+bls[co+3]));
  }
}

template<int ADDSUM>
__global__ __launch_bounds__(256)
void k_upd2_ln(const u16* __restrict__ hnb, const u16* __restrict__ Wp,
               const float* __restrict__ b2, const float* __restrict__ lng,
               const float* __restrict__ lnb, float* __restrict__ x,
               float* __restrict__ sumf, u16* __restrict__ xb){
  __shared__ u16 Ab[TM][KP];
  __shared__ u16 Wt[H][KP];
  __shared__ float bls[H], lgs[H], lbs[H];
  const int tid = threadIdx.x;
  const int wave = tid>>6, l = tid&63, l15 = l&15, quad = l>>4;
  const int wrow = wave*16, q8 = quad*8;
  const int rowbase = blockIdx.x*TM;
  if (tid < H){ bls[tid] = b2[tid]; lgs[tid] = lng[tid]; }
  else lbs[tid-H] = lnb[tid-H];
  f32x4 acc[8];
#pragma unroll
  for (int t=0;t<8;t++) acc[t] = (f32x4)(0.f);
  for (int kc=0; kc<H; kc+=KC){
    __syncthreads();
    STAGE_AB(hnb + (size_t)(rowbase + r_)*H + kc)
    STAGE_WT(Wp, 128, kc)
    __syncthreads();
    MFMA_TILES(Ab, 0, acc)
  }
  const int node = rowbase + wrow + l15;
  const size_t ro = (size_t)node*H;
  float y[8][4]; float s = 0.f, ss = 0.f;
#pragma unroll
  for (int t=0;t<8;t++){
    int co = t*16 + quad*4;
    float4 xv = *(const float4*)&x[ro + co];
    y[t][0] = xv.x + acc[t][0] + bls[co];
    y[t][1] = xv.y + acc[t][1] + bls[co+1];
    y[t][2] = xv.z + acc[t][2] + bls[co+2];
    y[t][3] = xv.w + acc[t][3] + bls[co+3];
#pragma unroll
    for (int r=0;r<4;r++){ s += y[t][r]; ss += y[t][r]*y[t][r]; }
  }
  s  += __shfl_xor(s, 16);  s  += __shfl_xor(s, 32);
  ss += __shfl_xor(ss, 16); ss += __shfl_xor(ss, 32);
  float mean = s*(1.0f/H);
  float var  = ss*(1.0f/H) - mean*mean;
  float inv  = rsqrtf(var + 1e-5f);
#pragma unroll
  for (int t=0;t<8;t++){
    int co = t*16 + quad*4;
    float4 o;
    o.x = (y[t][0]-mean)*inv*lgs[co]   + lbs[co];
    o.y = (y[t][1]-mean)*inv*lgs[co+1] + lbs[co+1];
    o.z = (y[t][2]-mean)*inv*lgs[co+2] + lbs[co+2];
    o.w = (y[t][3]-mean)*inv*lgs[co+3] + lbs[co+3];
    *(float4*)&x[ro + co] = o;
    if (ADDSUM){
      float4 sf = *(const float4*)&sumf[ro + co];
      sf.x += o.x; sf.y += o.y; sf.z += o.z; sf.w += o.w;
      *(float4*)&sumf[ro + co] = sf;
    }
    *(uint2*)&xb[ro + co] = pack4(o.x, o.y, o.z, o.w);
  }
}

template<int ACT, int OUTF32, int OUTBF>
__global__ __launch_bounds__(256)
void k_ngemm(const u16* __restrict__ A, const u16* __restrict__ Wp,
             const float* __restrict__ bias, float* __restrict__ outf,
             u16* __restrict__ outb){
  __shared__ u16 Ab[TM][KP];
  __shared__ u16 Wt[H][KP];
  __shared__ float bls[H];
  const int tid = threadIdx.x;
  const int wave = tid>>6, l = tid&63, l15 = l&15, quad = l>>4;
  const int wrow = wave*16, q8 = quad*8;
  const int rowbase = blockIdx.x*TM;
  if (tid < H) bls[tid] = bias[tid];
  f32x4 acc[8];
#pragma unroll
  for (int t=0;t<8;t++) acc[t] = (f32x4)(0.f);
  for (int kc=0; kc<H; kc+=KC){
    __syncthreads();
    STAGE_AB(A + (size_t)(rowbase + r_)*H + kc)
    STAGE_WT(Wp, 128, kc)
    __syncthreads();
    MFMA_TILES(Ab, 0, acc)
  }
  const int node = rowbase + wrow + l15;
#pragma unroll
  for (int t=0;t<8;t++){
    int co = t*16 + quad*4;
    float v0 = apply_act<ACT>(acc[t][0]+bls[co]);
    float v1 = apply_act<ACT>(acc[t][1]+bls[co+1]);
    float v2 = apply_act<ACT>(acc[t][2]+bls[co+2]);
    float v3 = apply_act<ACT>(acc[t][3]+bls[co+3]);
    if (OUTF32){
      float4 o; o.x=v0; o.y=v1; o.z=v2; o.w=v3;
      *(float4*)&outf[(size_t)node*H + co] = o;
    }
    if (OUTBF) *(uint2*)&outb[(size_t)node*H + co] = pack4(v0,v1,v2,v3);
  }
}

__global__ __launch_bounds__(256)
void k_gscore(const u16* __restrict__ aeb, const u16* __restrict__ Wp,
              const float* __restrict__ b1, const float* __restrict__ w2,
              const float* __restrict__ b2, float* __restrict__ g){
  __shared__ u16 Ab[TM][KP];
  __shared__ u16 Wt[H][KP];
  __shared__ float bls[H], w2s[H];
  const int tid = threadIdx.x;
  const int wave = tid>>6, l = tid&63, l15 = l&15, quad = l>>4;
  const int wrow = wave*16, q8 = quad*8;
  const int rowbase = blockIdx.x*TM;
  if (tid < H) bls[tid] = b1[tid];
  else w2s[tid-H] = w2[tid-H];
  f32x4 acc[8];
#pragma unroll
  for (int t=0;t<8;t++) acc[t] = (f32x4)(0.f);
  for (int kc=0; kc<H; kc+=KC){
    __syncthreads();
    STAGE_AB(aeb + (size_t)(rowbase + r_)*H + kc)
    STAGE_WT(Wp, 128, kc)
    __syncthreads();
    MFMA_TILES(Ab, 0, acc)
  }
  float p = 0.f;
#pragma unroll
  for (int t=0;t<8;t++){
    int co = t*16 + quad*4;
#pragma unroll
    for (int r=0;r<4;r++) p = fmaf(tanhf(acc[t][r]+bls[co+r]), w2s[co+r], p);
  }
  p += __shfl_xor(p, 16); p += __shfl_xor(p, 32);
  if (quad == 0) g[rowbase + wrow + l15] = p + b2[0];
}

// ---------------------------------------------------------------- pooling
__global__ void k_start(const int* __restrict__ batch, int* __restrict__ start){
  int b = threadIdx.x;
  if (b > NB) return;
  if (b == NB){ start[NB] = NN; return; }
  int lo = 0, hi = NN;
  while (lo < hi){ int mid = (lo+hi) >> 1; if (batch[mid] < b) lo = mid+1; else hi = mid; }
  start[b] = lo;
}

__global__ __launch_bounds__(256)
void k_pool(const int* __restrict__ start, const float* __restrict__ g,
            float* __restrict__ exb, const u16* __restrict__ hb,
            float* __restrict__ out){
  const int b = blockIdx.x;
  const int s = start[b], e = start[b+1];
  const int tid = threadIdx.x;
  __shared__ float red[4];
  __shared__ float s_gmax, s_den;
  __shared__ float part[2][H];

  float mx = -1e30f;
  for (int n = s + tid; n < e; n += 256) mx = fmaxf(mx, g[n]);
#pragma unroll
  for (int m=32;m>=1;m>>=1) mx = fmaxf(mx, __shfl_xor(mx, m, 64));
  if ((tid & 63) == 0) red[tid >> 6] = mx;
  __syncthreads();
  if (tid == 0){
    float v = fmaxf(fmaxf(red[0],red[1]), fmaxf(red[2],red[3]));
    s_gmax = (e > s) ? v : 0.0f;
  }
  __syncthreads();
  const float gmax = s_gmax;

  float sum = 0.f;
  for (int n = s + tid; n < e; n += 256){
    float ex = __expf(g[n] - gmax);
    exb[n] = ex;
    sum += ex;
  }
#pragma unroll
  for (int m=32;m>=1;m>>=1) sum += __shfl_xor(sum, m, 64);
  if ((tid & 63) == 0) red[tid >> 6] = sum;
  __syncthreads();
  if (tid == 0) s_den = red[0]+red[1]+red[2]+red[3];
  __syncthreads();
  const float den = s_den;

  const int col = tid & 127, rg = tid >> 7;
  float acc = 0.f;
  for (int n = s + rg; n < e; n += 2) acc = fmaf(exb[n], bf2f(hb[(size_t)n*H + col]), acc);
  part[rg][col] = acc;
  __syncthreads();
  if (tid < H){
    float v = part[0][tid] + part[1][tid];
    out[b*H + tid] = (den > 0.f) ? v/den : 0.0f;
  }
}

// ================================================================ host
extern "C" void kernel_launch(void* const* d_in, const int* in_sizes, int n_in,
                              void* d_out, int out_size, void* d_ws, size_t ws_size,
                              hipStream_t stream){
  const int*   Z      = (const int*)  d_in[0];
  const float* pos    = (const float*)d_in[1];
  const int*   batch  = (const int*)  d_in[2];
  const int*   ei     = (const int*)  d_in[3];
  const float* embed  = (const float*)d_in[4];
  const float* widths = (const float*)d_in[5];
  const float* ee_w1  = (const float*)d_in[6];
  const float* ee_b1  = (const float*)d_in[7];
  const float* ee_w2  = (const float*)d_in[8];
  const float* ee_b2  = (const float*)d_in[9];
  const float* msg_w1 = (const float*)d_in[10];
  const float* msg_b1 = (const float*)d_in[11];
  const float* msg_w2 = (const float*)d_in[12];
  const float* msg_b2 = (const float*)d_in[13];
  const float* gate_w = (const float*)d_in[14];
  const float* gate_b = (const float*)d_in[15];
  const float* upd_w1 = (const float*)d_in[16];
  const float* upd_b1 = (const float*)d_in[17];
  const float* upd_w2 = (const float*)d_in[18];
  const float* upd_b2 = (const float*)d_in[19];
  const float* ln_g   = (const float*)d_in[20];
  const float* ln_b   = (const float*)d_in[21];
  const float* gp_w1  = (const float*)d_in[22];
  const float* gp_b1  = (const float*)d_in[23];
  const float* gp_w2  = (const float*)d_in[24];
  const float* gp_b2  = (const float*)d_in[25];
  const float* pn_w   = (const float*)d_in[26];
  const float* pn_b   = (const float*)d_in[27];
  const float* ro_w1  = (const float*)d_in[28];
  const float* ro_b1  = (const float*)d_in[29];
  const float* ro_w2  = (const float*)d_in[30];
  const float* ro_b2  = (const float*)d_in[31];

  const int* srcv = ei;
  const int* dstv = ei + NE;

  // ---- workspace carve (64B-aligned) — ~32 MB total
  char* p0 = (char*)d_ws;
  char* p = p0;
  auto carve = [&](size_t bytes)->char*{ char* q = p; p += (bytes + 63) & ~(size_t)63; return q; };
  float* x     = (float*)carve((size_t)NH*4);
  float* aggr  = (float*)carve((size_t)NH*4);
  float* gsc   = (float*)carve((size_t)NN*4);
  float* exb   = (float*)carve((size_t)NN*4);
  int*   startb  = (int*)carve((size_t)(NB+2)*4);
  int*   estart  = (int*)carve((size_t)(NN+1)*4);
  int*   ecursor = (int*)carve((size_t)NN*4);
  int*   src_s   = (int*)carve((size_t)NE*4);
  int*   dst_s   = (int*)carve((size_t)NE*4);
  u16*   xb      = (u16*)carve((size_t)NH*2);
  u16*   packw   = (u16*)carve((size_t)4*LT2*2);
  u16*   packn   = (u16*)carve((size_t)(NG+65536)*2);
  u16*   nb1     = (u16*)carve((size_t)NH*2);   // y1 during edge phase
  u16*   nb2     = (u16*)carve((size_t)NH*2);   // y2 during edge phase

  float* out_af  = (float*)d_out;     // running sum of last-3 feats, then /3
  float* out_ae  = out_af + NH;
  float* out_gaf = out_ae + NH;

  // ---- once-per-call prep
  k_pack<<<dim3((LT2+255)/256, 4), 256, 0, stream>>>(ee_w1, ee_w2, msg_w1, msg_w2, gate_w, packw);
  k_packn<<<(NG+65536+255)/256, 256, 0, stream>>>(upd_w1, upd_w2, ro_w1, ro_w2, pn_w, gp_w1, packn);
  k_zero_i<<<(NN+255)/256, 256, 0, stream>>>(ecursor, NN);
  k_hist<<<NE/256, 256, 0, stream>>>(dstv, ecursor);
  k_scan<<<1, 1024, 0, stream>>>(ecursor, estart);
  k_scatter<<<NE/256, 256, 0, stream>>>(srcv, dstv, ecursor, src_s, dst_s);
  k_embed<<<NH/256, 256, 0, stream>>>(Z, embed, x, xb);
  k_zero<<<NH/256, 256, 0, stream>>>(out_af, NH);
  k_zero<<<NH/256, 256, 0, stream>>>(aggr, NH);   // layer 0 only; k_upd1 re-zeros

  for (int l=0; l<4; l++){
    const u16* pw  = packw + (size_t)l*LT2;
    const u16* pwn = packn + (size_t)l*LN_;
    k_y12<<<NN/TM, 256, 0, stream>>>(xb, pw + 82944, pw + 99328, msg_b1 + l*H, nb1, nb2);
    k_edge<<<NE/TM, 256, 0, stream>>>(src_s, dst_s, pos, widths, nb1, nb2, pw,
                                      ee_b1 + l*H, ee_b2 + l*H,
                                      msg_b2 + l*H, gate_b + l*H, aggr);
    k_upd1<<<NN/TM, 256, 0, stream>>>(aggr, xb, pwn, upd_b1 + l*H, nb1);
    if (l == 0)
      k_upd2_ln<0><<<NN/TM, 256, 0, stream>>>(nb1, pwn + 32768, upd_b2 + l*H,
                                              ln_g + l*H, ln_b + l*H, x, out_af, xb);
    else
      k_upd2_ln<1><<<NN/TM, 256, 0, stream>>>(nb1, pwn + 32768, upd_b2 + l*H,
                                              ln_g + l*H, ln_b + l*H, x, out_af, xb);
  }

  k_af<<<NH/256, 256, 0, stream>>>(out_af, nb1);
  k_ngemm<1,0,1><<<NN/TM, 256, 0, stream>>>(nb1, packn + NG,         ro_b1, nullptr, nb2);
  k_ngemm<0,1,1><<<NN/TM, 256, 0, stream>>>(nb2, packn + NG + 16384, ro_b2, out_ae, nb1);
  k_gscore<<<NN/TM, 256, 0, stream>>>(nb1, packn + NG + 49152, gp_b1, gp_w2, gp_b2, gsc);
  k_ngemm<1,0,1><<<NN/TM, 256, 0, stream>>>(nb1, packn + NG + 32768, pn_b, nullptr, nb2);
  k_start<<<1, 64, 0, stream>>>(batch, startb);
  k_pool<<<NB, 256, 0, stream>>>(startb, gsc, exb, nb2, out_gaf);
}

// Round 10
// 1007.289 us; speedup vs baseline: 1.1018x; 1.1018x over previous
//
#include <hip/hip_runtime.h>

#define NN   16384
#define NE   262144
#define NB   32
#define H    128
#define NH   (NN*H)
#define RBF  50
#define TM   64
#define KC   64
#define KP   72     // node-kernel LDS staging pitch (u16)
#define HBP  136    // Sb/Eb pitch (u16): 272 B rows
#define CHW  9216   // edge weight chunk: [128 rows][72 u16] (64 k + 8 pad)
#define LT2  115712 // packed edge weights per layer: 9*9216 + 16384(m1d) + 16384(m1s)
#define LN_  49152  // packed node weights per layer (u16)
#define NG   196608 // offset of global node weights in packn

typedef unsigned short u16;
typedef short bf16x8 __attribute__((ext_vector_type(8)));
typedef float f32x4 __attribute__((ext_vector_type(4)));

#if defined(__has_builtin)
#if __has_builtin(__builtin_amdgcn_cvt_pk_bf16_f32)
#define HAS_PK_BF16 1
#endif
#endif

__device__ __forceinline__ float sigmoidf_(float v){ return 1.0f/(1.0f + __expf(-v)); }
__device__ __forceinline__ float siluf_(float v){ return v * sigmoidf_(v); }
__device__ __forceinline__ u16 f2bf(float f){
  unsigned u = __float_as_uint(f);
  return (u16)((u + 0x7FFFu + ((u>>16)&1u)) >> 16);
}
__device__ __forceinline__ float bf2f(u16 v){ return __uint_as_float(((unsigned)v)<<16); }
__device__ __forceinline__ unsigned pk2(float a, float b){
#ifdef HAS_PK_BF16
  typedef __bf16 v2bf __attribute__((ext_vector_type(2)));
  v2bf v = __builtin_amdgcn_cvt_pk_bf16_f32(a, b);
  return __builtin_bit_cast(unsigned, v);
#else
  return (unsigned)f2bf(a) | ((unsigned)f2bf(b)<<16);
#endif
}
__device__ __forceinline__ uint2 pack4(float a, float b, float c, float d){
  uint2 r; r.x = pk2(a,b); r.y = pk2(c,d); return r;
}
__device__ __forceinline__ float blo(unsigned u){ return bf2f((u16)(u & 0xffffu)); }
__device__ __forceinline__ float bhi(unsigned u){ return bf2f((u16)(u >> 16)); }

template<int ACT>
__device__ __forceinline__ float apply_act(float v){ return (ACT==1) ? siluf_(v) : v; }

// ---- node-kernel LDS staging macros ----
#define STAGE_WT(GSRC, KPAD, K0) \
  _Pragma("unroll") \
  for (int i_=0;i_<4;i_++){ \
    int o_ = tid + i_*256; \
    int c_ = o_ >> 3, ko_ = (o_ & 7)*8; \
    *(uint4*)&Wt[c_][ko_] = *(const uint4*)((GSRC) + (size_t)c_*(KPAD) + (K0) + ko_); \
  }

#define STAGE_AB(ROWPTR) \
  _Pragma("unroll") \
  for (int i_=0;i_<2;i_++){ \
    int o_ = tid*2 + i_; \
    int r_ = o_ >> 3, ko_ = (o_ & 7)*8; \
    const u16* rp_ = (ROWPTR); \
    *(uint4*)&Ab[r_][ko_] = *(const uint4*)(rp_ + ko_); \
  }

#define STAGE_AF(FROWPTR) \
  _Pragma("unroll") \
  for (int i_=0;i_<2;i_++){ \
    int o_ = tid*2 + i_; \
    int r_ = o_ >> 3, ko_ = (o_ & 7)*8; \
    const float* rp_ = (FROWPTR); \
    float4 f0_ = *(const float4*)(rp_ + ko_); \
    float4 f1_ = *(const float4*)(rp_ + ko_ + 4); \
    uint4 pk_; \
    pk_.x = pk2(f0_.x, f0_.y); pk_.y = pk2(f0_.z, f0_.w); \
    pk_.z = pk2(f1_.x, f1_.y); pk_.w = pk2(f1_.z, f1_.w); \
    *(uint4*)&Ab[r_][ko_] = pk_; \
  }

#define MFMA_TILES(BBUF, KOFF, ACC) \
  _Pragma("unroll") \
  for (int ks_=0; ks_<KC; ks_+=32){ \
    bf16x8 bf_ = *(const bf16x8*)&BBUF[wrow + l15][(KOFF) + ks_ + q8]; \
    _Pragma("unroll") \
    for (int t_=0;t_<8;t_++){ \
      bf16x8 wf_ = *(const bf16x8*)&Wt[t_*16 + l15][ks_ + q8]; \
      ACC[t_] = __builtin_amdgcn_mfma_f32_16x16x32_bf16(wf_, bf_, ACC[t_], 0, 0, 0); \
    } \
  }

// ---- edge-kernel chunk MFMA: weights in flat WT[9216], B from wave-local buf ----
#define ECHUNK(BUF, OFF, ACC) { \
  bf16x8 b0_ = *(const bf16x8*)&BUF[l15][(OFF) + q8]; \
  bf16x8 b1_ = *(const bf16x8*)&BUF[l15][(OFF) + 32 + q8]; \
  _Pragma("unroll") \
  for (int t_=0;t_<8;t_++){ \
    bf16x8 w0_ = *(const bf16x8*)&WT[(t_*16+l15)*72 + q8]; \
    ACC[t_] = __builtin_amdgcn_mfma_f32_16x16x32_bf16(w0_, b0_, ACC[t_], 0, 0, 0); \
  } \
  _Pragma("unroll") \
  for (int t_=0;t_<8;t_++){ \
    bf16x8 w1_ = *(const bf16x8*)&WT[(t_*16+l15)*72 + 32 + q8]; \
    ACC[t_] = __builtin_amdgcn_mfma_f32_16x16x32_bf16(w1_, b1_, ACC[t_], 0, 0, 0); \
  } }

#define ECHUNK_RB(B0, B1, ACC) { \
  _Pragma("unroll") \
  for (int t_=0;t_<8;t_++){ \
    bf16x8 w0_ = *(const bf16x8*)&WT[(t_*16+l15)*72 + q8]; \
    ACC[t_] = __builtin_amdgcn_mfma_f32_16x16x32_bf16(w0_, B0, ACC[t_], 0, 0, 0); \
  } \
  _Pragma("unroll") \
  for (int t_=0;t_<8;t_++){ \
    bf16x8 w1_ = *(const bf16x8*)&WT[(t_*16+l15)*72 + 32 + q8]; \
    ACC[t_] = __builtin_amdgcn_mfma_f32_16x16x32_bf16(w1_, B1, ACC[t_], 0, 0, 0); \
  } }

// register-prefetch staging of one 18432B chunk (1152 uint4 slots, 256 threads)
#define LOADW(c) { \
  const uint4* gs_ = (const uint4*)(pw + (size_t)(c)*CHW); \
  p0 = gs_[tid]; p1 = gs_[tid+256]; p2 = gs_[tid+512]; p3 = gs_[tid+768]; \
  if (tid < 128) p4 = gs_[tid+1024]; }
#define STOREW() { \
  uint4* wd_ = (uint4*)WT; \
  wd_[tid] = p0; wd_[tid+256] = p1; wd_[tid+512] = p2; wd_[tid+768] = p3; \
  if (tid < 128) wd_[tid+1024] = p4; }

// ---------------------------------------------------------------- utility
__global__ void k_zero(float* __restrict__ p, int n){
  int i = blockIdx.x*256 + threadIdx.x; if (i < n) p[i] = 0.f;
}
__global__ void k_zero_i(int* __restrict__ p, int n){
  int i = blockIdx.x*256 + threadIdx.x; if (i < n) p[i] = 0;
}
__global__ void k_embed(const int* __restrict__ z, const float* __restrict__ emb,
                        float* __restrict__ x, u16* __restrict__ xb){
  int i = blockIdx.x*256 + threadIdx.x;
  int n = i >> 7, h = i & 127;
  float v = emb[z[n]*H + h];
  x[i] = v; xb[i] = f2bf(v);
}
__global__ void k_af(float* __restrict__ io, u16* __restrict__ ob){
  int i = blockIdx.x*256 + threadIdx.x;
  float v = io[i]*(1.0f/3.0f);
  io[i] = v; ob[i] = f2bf(v);
}

// ---------------------------------------------------------------- weight packing
// Edge layout per layer: chunks c=0..8 of [128][72] (64 valid k):
// 0:ee1 1,2:ee2 3,4:m1e 5,6:gate 7,8:msg2 ; then m1d dense @82944, m1s dense @99328.
__global__ void k_pack(const float* __restrict__ ee_w1, const float* __restrict__ ee_w2,
                       const float* __restrict__ msg_w1, const float* __restrict__ msg_w2,
                       const float* __restrict__ gate_w, u16* __restrict__ out){
  int idx = blockIdx.x*256 + threadIdx.x;
  int l = blockIdx.y;
  if (idx >= LT2) return;
  u16* o = out + (size_t)l*LT2;
  float v = 0.f;
  if (idx < 82944){
    int c = idx / CHW, r = idx % CHW, row = r / 72, col = r % 72;
    if (col < 64){
      if (c == 0)      v = (col < RBF) ? ee_w1[(size_t)l*RBF*H + col*H + row] : 0.f;
      else if (c <= 2) v = ee_w2 [(size_t)l*H*H + (64*(c-1)+col)*H + row];
      else if (c <= 4) v = msg_w1[(size_t)l*3*H*H + (256 + 64*(c-3)+col)*H + row];
      else if (c <= 6) v = gate_w[(size_t)l*H*H + (64*(c-5)+col)*H + row];
      else             v = msg_w2[(size_t)l*H*H + (64*(c-7)+col)*H + row];
    }
  } else if (idx < 99328){
    int j = idx - 82944; int row = j >> 7, k = j & 127;
    v = msg_w1[(size_t)l*3*H*H + k*H + row];
  } else {
    int j = idx - 99328; int row = j >> 7, k = j & 127;
    v = msg_w1[(size_t)l*3*H*H + (128+k)*H + row];
  }
  o[idx] = f2bf(v);
}

__global__ void k_packn(const float* __restrict__ upd_w1, const float* __restrict__ upd_w2,
                        const float* __restrict__ ro_w1, const float* __restrict__ ro_w2,
                        const float* __restrict__ pn_w, const float* __restrict__ gp_w1,
                        u16* __restrict__ out){
  int idx = blockIdx.x*256 + threadIdx.x;
  if (idx >= NG + 65536) return;
  float v;
  if (idx < NG){
    int l = idx / LN_, j = idx % LN_;
    if (j < 32768){ int c = j>>8, k = j&255; v = upd_w1[(size_t)l*256*H + k*H + c]; }
    else { int j2 = j-32768; int c = j2>>7, k = j2&127; v = upd_w2[(size_t)l*H*H + k*H + c]; }
  } else {
    int j = idx - NG; int m = j >> 14; int j2 = j & 16383;
    int c = j2>>7, k = j2&127;
    const float* W = (m==0) ? ro_w1 : (m==1) ? ro_w2 : (m==2) ? pn_w : gp_w1;
    v = W[k*H + c];
  }
  out[idx] = f2bf(v);
}

// ---------------------------------------------------------------- edge sort by dst
__global__ void k_hist(const int* __restrict__ dstv, int* __restrict__ cnt){
  int e = blockIdx.x*256 + threadIdx.x;
  if (e < NE) atomicAdd(&cnt[dstv[e]], 1);
}
__global__ __launch_bounds__(1024)
void k_scan(int* __restrict__ cnt, int* __restrict__ start){
  __shared__ int ps[1024];
  int tid = threadIdx.x;
  int base = tid*16;
  int loc[16]; int s = 0;
#pragma unroll
  for (int i=0;i<16;i++){ loc[i] = s; s += cnt[base+i]; }
  ps[tid] = s; __syncthreads();
  for (int off=1; off<1024; off<<=1){
    int v = (tid>=off) ? ps[tid-off] : 0;
    __syncthreads();
    ps[tid] += v;
    __syncthreads();
  }
  int pre = (tid>0) ? ps[tid-1] : 0;
#pragma unroll
  for (int i=0;i<16;i++){ int v = pre + loc[i]; start[base+i] = v; cnt[base+i] = v; }
  if (tid == 0) start[NN] = NE;
}
__global__ void k_scatter(const int* __restrict__ srcv, const int* __restrict__ dstv,
                          int* __restrict__ cursor, int* __restrict__ src_s,
                          int* __restrict__ dst_s){
  int e = blockIdx.x*256 + threadIdx.x;
  if (e >= NE) return;
  int d = dstv[e];
  int p = atomicAdd(&cursor[d], 1);
  src_s[p] = srcv[e]; dst_s[p] = d;
}

// ---------------------------------------------------------------- FUSED edge pipeline
// R8 structure: dual wave-private Eb/Sb, LDS-staged weights via register prefetch.
__global__ __launch_bounds__(256)
void k_edge(const int* __restrict__ src_s, const int* __restrict__ dst_s,
            const float* __restrict__ pos, const float* __restrict__ widths,
            const u16* __restrict__ y1b, const u16* __restrict__ y2b,
            const u16* __restrict__ pw,
            const float* __restrict__ b_ee1, const float* __restrict__ b_ee2,
            const float* __restrict__ b_m2, const float* __restrict__ b_g,
            float* __restrict__ aggr){
  __shared__ u16 WT[CHW];            // 18.4 KB weight chunk
  __shared__ u16 SB[4][16][HBP];     // 17.4 KB wave-local
  __shared__ u16 EB[4][16][HBP];     // 17.4 KB wave-local (total 53.2 KB)
  const int tid = threadIdx.x;
  const int wave = tid>>6, l = tid&63, l15 = l&15, quad = l>>4, q8 = quad*8;
  const int ebase = blockIdx.x*TM + wave*16;
  const int eid   = ebase + l15;
  u16 (*Sb)[HBP] = SB[wave];
  u16 (*Eb)[HBP] = EB[wave];

  // ---- per-lane edge geometry + RBF fragments (registers)
  const int esrc = src_s[eid], edst = dst_s[eid];
  float dx = pos[3*edst]   - pos[3*esrc];
  float dy = pos[3*edst+1] - pos[3*esrc+1];
  float dz = pos[3*edst+2] - pos[3*esrc+2];
  float dist = sqrtf(dx*dx + dy*dy + dz*dz);
  float cut  = (dist < 5.0f) ? 0.5f*(__cosf(0.62831853f*dist) + 1.0f) : 0.0f;
  bf16x8 rb0, rb1;
#pragma unroll
  for (int j=0;j<8;j++){
    int k0 = q8 + j, k1 = 32 + q8 + j;
    float t0 = dist - 0.10204082f*(float)k0;
    float t1 = dist - 0.10204082f*(float)k1;
    float w0 = widths[k0 < RBF ? k0 : 0], w1 = widths[k1 < RBF ? k1 : 0];
    float v0 = (k0 < RBF) ? __expf(-(1.0f/(2.0f*w0*w0))*t0*t0)*cut : 0.f;
    float v1 = (k1 < RBF) ? __expf(-(1.0f/(2.0f*w1*w1))*t1*t1)*cut : 0.f;
    ((u16*)&rb0)[j] = f2bf(v0);
    ((u16*)&rb1)[j] = f2bf(v1);
  }

  // ---- prefetch y1[dst], y2[src] gathers (hidden behind the whole ee phase)
  uint2 gy1[8], gy2[8];
#pragma unroll
  for (int t=0;t<8;t++){
    int co = t*16 + quad*4;
    gy1[t] = *(const uint2*)&y1b[(size_t)edst*H + co];
    gy2[t] = *(const uint2*)&y2b[(size_t)esrc*H + co];
  }

  uint4 p0, p1, p2, p3, p4;
  LOADW(0) STOREW() LOADW(1)
  __syncthreads();                       // chunk0 (ee1) ready

  f32x4 acc[8];
#pragma unroll
  for (int t=0;t<8;t++) acc[t] = (f32x4)(0.f);
  ECHUNK_RB(rb0, rb1, acc)               // ee1 (K=64)
#pragma unroll
  for (int t=0;t<8;t++){                 // hidden silu -> Sb
    int co = t*16 + quad*4;
    float4 b = *(const float4*)(b_ee1 + co);
    *(uint2*)&Sb[l15][co] = pack4(
      siluf_(acc[t][0]+b.x), siluf_(acc[t][1]+b.y),
      siluf_(acc[t][2]+b.z), siluf_(acc[t][3]+b.w));
  }
  __syncthreads(); STOREW(); __syncthreads(); LOADW(2)
#pragma unroll
  for (int t=0;t<8;t++) acc[t] = (f32x4)(0.f);
  ECHUNK(Sb, 0, acc)                     // ee2 k0-63
  __syncthreads(); STOREW(); __syncthreads(); LOADW(3)
  ECHUNK(Sb, 64, acc)                    // ee2 k64-127
#pragma unroll
  for (int t=0;t<8;t++){                 // ee -> Eb
    int co = t*16 + quad*4;
    float4 b = *(const float4*)(b_ee2 + co);
    *(uint2*)&Eb[l15][co] = pack4(
      acc[t][0]+b.x, acc[t][1]+b.y, acc[t][2]+b.z, acc[t][3]+b.w);
  }
  __syncthreads(); STOREW(); __syncthreads(); LOADW(4)
#pragma unroll
  for (int t=0;t<8;t++) acc[t] = (f32x4)(0.f);
  ECHUNK(Eb, 0, acc)                     // m1e k0-63
  __syncthreads(); STOREW(); __syncthreads(); LOADW(5)
  ECHUNK(Eb, 64, acc)                    // m1e k64-127
#pragma unroll
  for (int t=0;t<8;t++){                 // msg hidden: + y1[dst] + y2[src], silu -> Sb
    int co = t*16 + quad*4;
    float v0 = acc[t][0] + blo(gy1[t].x) + blo(gy2[t].x);
    float v1 = acc[t][1] + bhi(gy1[t].x) + bhi(gy2[t].x);
    float v2 = acc[t][2] + blo(gy1[t].y) + blo(gy2[t].y);
    float v3 = acc[t][3] + bhi(gy1[t].y) + bhi(gy2[t].y);
    *(uint2*)&Sb[l15][co] = pack4(siluf_(v0), siluf_(v1), siluf_(v2), siluf_(v3));
  }
  __syncthreads(); STOREW(); __syncthreads(); LOADW(6)
  f32x4 accG[8];
#pragma unroll
  for (int t=0;t<8;t++) accG[t] = (f32x4)(0.f);
  ECHUNK(Eb, 0, accG)                    // gate k0-63
  __syncthreads(); STOREW(); __syncthreads(); LOADW(7)
  ECHUNK(Eb, 64, accG)                   // gate k64-127
  __syncthreads(); STOREW(); __syncthreads(); LOADW(8)
#pragma unroll
  for (int t=0;t<8;t++) acc[t] = (f32x4)(0.f);
  ECHUNK(Sb, 0, acc)                     // msg2 k0-63
  __syncthreads(); STOREW(); __syncthreads();
  ECHUNK(Sb, 64, acc)                    // msg2 k64-127
#pragma unroll
  for (int t=0;t<8;t++){                 // gated message -> Sb
    int co = t*16 + quad*4;
    float4 bm = *(const float4*)(b_m2 + co);
    float4 bg = *(const float4*)(b_g + co);
    float m0 = acc[t][0]+bm.x, m1 = acc[t][1]+bm.y;
    float m2 = acc[t][2]+bm.z, m3 = acc[t][3]+bm.w;
    float g0 = sigmoidf_(accG[t][0]+bg.x), g1 = sigmoidf_(accG[t][1]+bg.y);
    float g2 = sigmoidf_(accG[t][2]+bg.z), g3 = sigmoidf_(accG[t][3]+bg.w);
    *(uint2*)&Sb[l15][co] = pack4(m0*g0, m1*g1, m2*g2, m3*g3);
  }

  // ---- wave-local segmented reduce (dst-sorted): 2 cols per lane over 16 rows
  {
    int c0 = l*2;
    float a0 = 0.f, a1 = 0.f;
    int cur = dst_s[ebase];
#pragma unroll
    for (int r=0; r<16; r++){
      int d = dst_s[ebase + r];
      if (d != cur){
        atomicAdd(&aggr[(size_t)cur*H + c0],     a0);
        atomicAdd(&aggr[(size_t)cur*H + c0 + 1], a1);
        a0 = 0.f; a1 = 0.f; cur = d;
      }
      unsigned pv = *(const unsigned*)&Sb[r][c0];
      a0 += blo(pv); a1 += bhi(pv);
    }
    atomicAdd(&aggr[(size_t)cur*H + c0],     a0);
    atomicAdd(&aggr[(size_t)cur*H + c0 + 1], a1);
  }
}

// ---------------------------------------------------------------- node MFMA kernels
// standalone y1 = x@W1d + b_m1 ; y2 = x@W1s  (layer 0 only)
__global__ __launch_bounds__(256)
void k_y12(const u16* __restrict__ xb, const u16* __restrict__ Wd,
           const u16* __restrict__ Ws, const float* __restrict__ b1,
           u16* __restrict__ y1, u16* __restrict__ y2){
  __shared__ u16 Ab[TM][KP];
  __shared__ u16 Wt[H][KP];
  __shared__ float bls[H];
  const int tid = threadIdx.x;
  const int wave = tid>>6, l = tid&63, l15 = l&15, quad = l>>4;
  const int wrow = wave*16, q8 = quad*8;
  const int rowbase = blockIdx.x*TM;
  if (tid < H) bls[tid] = b1[tid];
  f32x4 a1[8], a2[8];
#pragma unroll
  for (int t=0;t<8;t++){ a1[t] = (f32x4)(0.f); a2[t] = (f32x4)(0.f); }
  for (int kc=0; kc<H; kc+=KC){
    __syncthreads();
    STAGE_AB(xb + (size_t)(rowbase + r_)*H + kc)
    STAGE_WT(Wd, 128, kc)
    __syncthreads();
    MFMA_TILES(Ab, 0, a1)
    __syncthreads();
    STAGE_WT(Ws, 128, kc)
    __syncthreads();
    MFMA_TILES(Ab, 0, a2)
  }
  const int node = rowbase + wrow + l15;
#pragma unroll
  for (int t=0;t<8;t++){
    int co = t*16 + quad*4;
    *(uint2*)&y1[(size_t)node*H + co] = pack4(
      a1[t][0]+bls[co], a1[t][1]+bls[co+1], a1[t][2]+bls[co+2], a1[t][3]+bls[co+3]);
    *(uint2*)&y2[(size_t)node*H + co] = pack4(
      a2[t][0], a2[t][1], a2[t][2], a2[t][3]);
  }
}

// upd1: concat(aggr f32, xb bf16) @ W (K=256) + b, silu -> bf16 ; re-zeros aggr rows
__global__ __launch_bounds__(256)
void k_upd1(float* __restrict__ aggr, const u16* __restrict__ xb,
            const u16* __restrict__ Wp, const float* __restrict__ bias,
            u16* __restrict__ outb){
  __shared__ u16 Ab[TM][KP];
  __shared__ u16 Wt[H][KP];
  __shared__ float bls[H];
  const int tid = threadIdx.x;
  const int wave = tid>>6, l = tid&63, l15 = l&15, quad = l>>4;
  const int wrow = wave*16, q8 = quad*8;
  const int rowbase = blockIdx.x*TM;
  if (tid < H) bls[tid] = bias[tid];
  f32x4 acc[8];
#pragma unroll
  for (int t=0;t<8;t++) acc[t] = (f32x4)(0.f);
  for (int kc=0; kc<256; kc+=KC){
    __syncthreads();
    if (kc < 128) { STAGE_AF(aggr + (size_t)(rowbase + r_)*H + kc) }
    else          { STAGE_AB(xb + (size_t)(rowbase + r_)*H + (kc-128)) }
    STAGE_WT(Wp, 256, kc)
    __syncthreads();
    MFMA_TILES(Ab, 0, acc)
  }
  // re-zero this block's aggr rows for the next layer
  {
    float4 z = make_float4(0.f,0.f,0.f,0.f);
#pragma unroll
    for (int i=0;i<8;i++){
      int o = tid + i*256;
      *(float4*)&aggr[(size_t)rowbase*H + (size_t)o*4] = z;
    }
  }
  const int node = rowbase + wrow + l15;
#pragma unroll
  for (int t=0;t<8;t++){
    int co = t*16 + quad*4;
    *(uint2*)&outb[(size_t)node*H + co] = pack4(
      siluf_(acc[t][0]+bls[co]),   siluf_(acc[t][1]+bls[co+1]),
      siluf_(acc[t][2]+bls[co+2]), siluf_(acc[t][3]+bls[co+3]));
  }
}

// upd2 + residual + LayerNorm (+sumf) ; optionally fused next-layer y1/y2
template<int ADDSUM, int DOY12>
__global__ __launch_bounds__(256)
void k_upd2_ln(const u16* __restrict__ hnb, const u16* __restrict__ Wp,
               const float* __restrict__ b2, const float* __restrict__ lng,
               const float* __restrict__ lnb, float* __restrict__ x,
               float* __restrict__ sumf, u16* __restrict__ xb,
               const u16* __restrict__ Wdn, const u16* __restrict__ Wsn,
               const float* __restrict__ b1n,
               u16* __restrict__ y1, u16* __restrict__ y2){
  __shared__ u16 Ab[TM][KP];
  __shared__ u16 Wt[H][KP];
  __shared__ float bls[H], lgs[H], lbs[H], b1s[H];
  const int tid = threadIdx.x;
  const int wave = tid>>6, l = tid&63, l15 = l&15, quad = l>>4;
  const int wrow = wave*16, q8 = quad*8;
  const int rowbase = blockIdx.x*TM;
  if (tid < H){ bls[tid] = b2[tid]; lgs[tid] = lng[tid]; if (DOY12) b1s[tid] = b1n[tid]; }
  else lbs[tid-H] = lnb[tid-H];
  f32x4 acc[8];
#pragma unroll
  for (int t=0;t<8;t++) acc[t] = (f32x4)(0.f);
  for (int kc=0; kc<H; kc+=KC){
    __syncthreads();
    STAGE_AB(hnb + (size_t)(rowbase + r_)*H + kc)
    STAGE_WT(Wp, 128, kc)
    __syncthreads();
    MFMA_TILES(Ab, 0, acc)
  }
  const int node = rowbase + wrow + l15;
  const size_t ro = (size_t)node*H;
  float y[8][4]; float s = 0.f, ss = 0.f;
#pragma unroll
  for (int t=0;t<8;t++){
    int co = t*16 + quad*4;
    float4 xv = *(const float4*)&x[ro + co];
    y[t][0] = xv.x + acc[t][0] + bls[co];
    y[t][1] = xv.y + acc[t][1] + bls[co+1];
    y[t][2] = xv.z + acc[t][2] + bls[co+2];
    y[t][3] = xv.w + acc[t][3] + bls[co+3];
#pragma unroll
    for (int r=0;r<4;r++){ s += y[t][r]; ss += y[t][r]*y[t][r]; }
  }
  s  += __shfl_xor(s, 16);  s  += __shfl_xor(s, 32);
  ss += __shfl_xor(ss, 16); ss += __shfl_xor(ss, 32);
  float mean = s*(1.0f/H);
  float var  = ss*(1.0f/H) - mean*mean;
  float inv  = rsqrtf(var + 1e-5f);
#pragma unroll
  for (int t=0;t<8;t++){
    int co = t*16 + quad*4;
    float4 o;
    o.x = (y[t][0]-mean)*inv*lgs[co]   + lbs[co];
    o.y = (y[t][1]-mean)*inv*lgs[co+1] + lbs[co+1];
    o.z = (y[t][2]-mean)*inv*lgs[co+2] + lbs[co+2];
    o.w = (y[t][3]-mean)*inv*lgs[co+3] + lbs[co+3];
    *(float4*)&x[ro + co] = o;
    if (ADDSUM){
      float4 sf = *(const float4*)&sumf[ro + co];
      sf.x += o.x; sf.y += o.y; sf.z += o.z; sf.w += o.w;
      *(float4*)&sumf[ro + co] = sf;
    }
    *(uint2*)&xb[ro + co] = pack4(o.x, o.y, o.z, o.w);
    y[t][0] = o.x; y[t][1] = o.y; y[t][2] = o.z; y[t][3] = o.w;   // keep for y12
  }

  if (DOY12){
    // next-layer y1 = x@W1d + b1n ; y2 = x@W1s — x rows are in y[][] registers.
    f32x4 a1[8], a2[8];
#pragma unroll
    for (int t=0;t<8;t++){ a1[t] = (f32x4)(0.f); a2[t] = (f32x4)(0.f); }
    for (int kc=0; kc<H; kc+=KC){
      // stage this wave's 16 x-rows, cols [kc,kc+64) into Ab (wave-local rows)
#pragma unroll
      for (int t=kc/16; t<kc/16+4; t++){
        int co = t*16 + quad*4;
        *(uint2*)&Ab[wrow + l15][co - kc] = pack4(y[t][0], y[t][1], y[t][2], y[t][3]);
      }
      __syncthreads();
      STAGE_WT(Wdn, 128, kc)
      __syncthreads();
      MFMA_TILES(Ab, 0, a1)
      __syncthreads();
      STAGE_WT(Wsn, 128, kc)
      __syncthreads();
      MFMA_TILES(Ab, 0, a2)
      __syncthreads();
    }
#pragma unroll
    for (int t=0;t<8;t++){
      int co = t*16 + quad*4;
      *(uint2*)&y1[ro + co] = pack4(
        a1[t][0]+b1s[co], a1[t][1]+b1s[co+1], a1[t][2]+b1s[co+2], a1[t][3]+b1s[co+3]);
      *(uint2*)&y2[ro + co] = pack4(a2[t][0], a2[t][1], a2[t][2], a2[t][3]);
    }
  }
}

template<int ACT, int OUTF32, int OUTBF>
__global__ __launch_bounds__(256)
void k_ngemm(const u16* __restrict__ A, const u16* __restrict__ Wp,
             const float* __restrict__ bias, float* __restrict__ outf,
             u16* __restrict__ outb){
  __shared__ u16 Ab[TM][KP];
  __shared__ u16 Wt[H][KP];
  __shared__ float bls[H];
  const int tid = threadIdx.x;
  const int wave = tid>>6, l = tid&63, l15 = l&15, quad = l>>4;
  const int wrow = wave*16, q8 = quad*8;
  const int rowbase = blockIdx.x*TM;
  if (tid < H) bls[tid] = bias[tid];
  f32x4 acc[8];
#pragma unroll
  for (int t=0;t<8;t++) acc[t] = (f32x4)(0.f);
  for (int kc=0; kc<H; kc+=KC){
    __syncthreads();
    STAGE_AB(A + (size_t)(rowbase + r_)*H + kc)
    STAGE_WT(Wp, 128, kc)
    __syncthreads();
    MFMA_TILES(Ab, 0, acc)
  }
  const int node = rowbase + wrow + l15;
#pragma unroll
  for (int t=0;t<8;t++){
    int co = t*16 + quad*4;
    float v0 = apply_act<ACT>(acc[t][0]+bls[co]);
    float v1 = apply_act<ACT>(acc[t][1]+bls[co+1]);
    float v2 = apply_act<ACT>(acc[t][2]+bls[co+2]);
    float v3 = apply_act<ACT>(acc[t][3]+bls[co+3]);
    if (OUTF32){
      float4 o; o.x=v0; o.y=v1; o.z=v2; o.w=v3;
      *(float4*)&outf[(size_t)node*H + co] = o;
    }
    if (OUTBF) *(uint2*)&outb[(size_t)node*H + co] = pack4(v0,v1,v2,v3);
  }
}

__global__ __launch_bounds__(256)
void k_gscore(const u16* __restrict__ aeb, const u16* __restrict__ Wp,
              const float* __restrict__ b1, const float* __restrict__ w2,
              const float* __restrict__ b2, float* __restrict__ g){
  __shared__ u16 Ab[TM][KP];
  __shared__ u16 Wt[H][KP];
  __shared__ float bls[H], w2s[H];
  const int tid = threadIdx.x;
  const int wave = tid>>6, l = tid&63, l15 = l&15, quad = l>>4;
  const int wrow = wave*16, q8 = quad*8;
  const int rowbase = blockIdx.x*TM;
  if (tid < H) bls[tid] = b1[tid];
  else w2s[tid-H] = w2[tid-H];
  f32x4 acc[8];
#pragma unroll
  for (int t=0;t<8;t++) acc[t] = (f32x4)(0.f);
  for (int kc=0; kc<H; kc+=KC){
    __syncthreads();
    STAGE_AB(aeb + (size_t)(rowbase + r_)*H + kc)
    STAGE_WT(Wp, 128, kc)
    __syncthreads();
    MFMA_TILES(Ab, 0, acc)
  }
  float p = 0.f;
#pragma unroll
  for (int t=0;t<8;t++){
    int co = t*16 + quad*4;
#pragma unroll
    for (int r=0;r<4;r++) p = fmaf(tanhf(acc[t][r]+bls[co+r]), w2s[co+r], p);
  }
  p += __shfl_xor(p, 16); p += __shfl_xor(p, 32);
  if (quad == 0) g[rowbase + wrow + l15] = p + b2[0];
}

// ---------------------------------------------------------------- pooling
__global__ void k_start(const int* __restrict__ batch, int* __restrict__ start){
  int b = threadIdx.x;
  if (b > NB) return;
  if (b == NB){ start[NB] = NN; return; }
  int lo = 0, hi = NN;
  while (lo < hi){ int mid = (lo+hi) >> 1; if (batch[mid] < b) lo = mid+1; else hi = mid; }
  start[b] = lo;
}

__global__ __launch_bounds__(256)
void k_pool(const int* __restrict__ start, const float* __restrict__ g,
            float* __restrict__ exb, const u16* __restrict__ hb,
            float* __restrict__ out){
  const int b = blockIdx.x;
  const int s = start[b], e = start[b+1];
  const int tid = threadIdx.x;
  __shared__ float red[4];
  __shared__ float s_gmax, s_den;
  __shared__ float part[2][H];

  float mx = -1e30f;
  for (int n = s + tid; n < e; n += 256) mx = fmaxf(mx, g[n]);
#pragma unroll
  for (int m=32;m>=1;m>>=1) mx = fmaxf(mx, __shfl_xor(mx, m, 64));
  if ((tid & 63) == 0) red[tid >> 6] = mx;
  __syncthreads();
  if (tid == 0){
    float v = fmaxf(fmaxf(red[0],red[1]), fmaxf(red[2],red[3]));
    s_gmax = (e > s) ? v : 0.0f;
  }
  __syncthreads();
  const float gmax = s_gmax;

  float sum = 0.f;
  for (int n = s + tid; n < e; n += 256){
    float ex = __expf(g[n] - gmax);
    exb[n] = ex;
    sum += ex;
  }
#pragma unroll
  for (int m=32;m>=1;m>>=1) sum += __shfl_xor(sum, m, 64);
  if ((tid & 63) == 0) red[tid >> 6] = sum;
  __syncthreads();
  if (tid == 0) s_den = red[0]+red[1]+red[2]+red[3];
  __syncthreads();
  const float den = s_den;

  const int col = tid & 127, rg = tid >> 7;
  float acc = 0.f;
  for (int n = s + rg; n < e; n += 2) acc = fmaf(exb[n], bf2f(hb[(size_t)n*H + col]), acc);
  part[rg][col] = acc;
  __syncthreads();
  if (tid < H){
    float v = part[0][tid] + part[1][tid];
    out[b*H + tid] = (den > 0.f) ? v/den : 0.0f;
  }
}

// ================================================================ host
extern "C" void kernel_launch(void* const* d_in, const int* in_sizes, int n_in,
                              void* d_out, int out_size, void* d_ws, size_t ws_size,
                              hipStream_t stream){
  const int*   Z      = (const int*)  d_in[0];
  const float* pos    = (const float*)d_in[1];
  const int*   batch  = (const int*)  d_in[2];
  const int*   ei     = (const int*)  d_in[3];
  const float* embed  = (const float*)d_in[4];
  const float* widths = (const float*)d_in[5];
  const float* ee_w1  = (const float*)d_in[6];
  const float* ee_b1  = (const float*)d_in[7];
  const float* ee_w2  = (const float*)d_in[8];
  const float* ee_b2  = (const float*)d_in[9];
  const float* msg_w1 = (const float*)d_in[10];
  const float* msg_b1 = (const float*)d_in[11];
  const float* msg_w2 = (const float*)d_in[12];
  const float* msg_b2 = (const float*)d_in[13];
  const float* gate_w = (const float*)d_in[14];
  const float* gate_b = (const float*)d_in[15];
  const float* upd_w1 = (const float*)d_in[16];
  const float* upd_b1 = (const float*)d_in[17];
  const float* upd_w2 = (const float*)d_in[18];
  const float* upd_b2 = (const float*)d_in[19];
  const float* ln_g   = (const float*)d_in[20];
  const float* ln_b   = (const float*)d_in[21];
  const float* gp_w1  = (const float*)d_in[22];
  const float* gp_b1  = (const float*)d_in[23];
  const float* gp_w2  = (const float*)d_in[24];
  const float* gp_b2  = (const float*)d_in[25];
  const float* pn_w   = (const float*)d_in[26];
  const float* pn_b   = (const float*)d_in[27];
  const float* ro_w1  = (const float*)d_in[28];
  const float* ro_b1  = (const float*)d_in[29];
  const float* ro_w2  = (const float*)d_in[30];
  const float* ro_b2  = (const float*)d_in[31];

  const int* srcv = ei;
  const int* dstv = ei + NE;

  // ---- workspace carve (64B-aligned) — ~32 MB total
  char* p0 = (char*)d_ws;
  char* p = p0;
  auto carve = [&](size_t bytes)->char*{ char* q = p; p += (bytes + 63) & ~(size_t)63; return q; };
  float* x     = (float*)carve((size_t)NH*4);
  float* aggr  = (float*)carve((size_t)NH*4);
  float* gsc   = (float*)carve((size_t)NN*4);
  float* exb   = (float*)carve((size_t)NN*4);
  int*   startb  = (int*)carve((size_t)(NB+2)*4);
  int*   estart  = (int*)carve((size_t)(NN+1)*4);
  int*   ecursor = (int*)carve((size_t)NN*4);
  int*   src_s   = (int*)carve((size_t)NE*4);
  int*   dst_s   = (int*)carve((size_t)NE*4);
  u16*   xb      = (u16*)carve((size_t)NH*2);
  u16*   packw   = (u16*)carve((size_t)4*LT2*2);
  u16*   packn   = (u16*)carve((size_t)(NG+65536)*2);
  u16*   nb1     = (u16*)carve((size_t)NH*2);   // y1 during edge phase
  u16*   nb2     = (u16*)carve((size_t)NH*2);   // y2 during edge phase

  float* out_af  = (float*)d_out;     // running sum of last-3 feats, then /3
  float* out_ae  = out_af + NH;
  float* out_gaf = out_ae + NH;

  // ---- once-per-call prep
  k_pack<<<dim3((LT2+255)/256, 4), 256, 0, stream>>>(ee_w1, ee_w2, msg_w1, msg_w2, gate_w, packw);
  k_packn<<<(NG+65536+255)/256, 256, 0, stream>>>(upd_w1, upd_w2, ro_w1, ro_w2, pn_w, gp_w1, packn);
  k_zero_i<<<(NN+255)/256, 256, 0, stream>>>(ecursor, NN);
  k_hist<<<NE/256, 256, 0, stream>>>(dstv, ecursor);
  k_scan<<<1, 1024, 0, stream>>>(ecursor, estart);
  k_scatter<<<NE/256, 256, 0, stream>>>(srcv, dstv, ecursor, src_s, dst_s);
  k_embed<<<NH/256, 256, 0, stream>>>(Z, embed, x, xb);
  k_zero<<<NH/256, 256, 0, stream>>>(out_af, NH);
  k_zero<<<NH/256, 256, 0, stream>>>(aggr, NH);   // layer 0 only; k_upd1 re-zeros

  // layer-0 y1/y2 (subsequent layers fused into k_upd2_ln)
  k_y12<<<NN/TM, 256, 0, stream>>>(xb, packw + 82944, packw + 99328, msg_b1, nb1, nb2);

  for (int l=0; l<4; l++){
    const u16* pw  = packw + (size_t)l*LT2;
    const u16* pwn = packn + (size_t)l*LN_;
    const u16* pwN = packw + (size_t)(l+1)*LT2;   // next-layer edge pack (for fused y12)
    k_edge<<<NE/TM, 256, 0, stream>>>(src_s, dst_s, pos, widths, nb1, nb2, pw,
                                      ee_b1 + l*H, ee_b2 + l*H,
                                      msg_b2 + l*H, gate_b + l*H, aggr);
    k_upd1<<<NN/TM, 256, 0, stream>>>(aggr, xb, pwn, upd_b1 + l*H, nb1);
    if (l == 0)
      k_upd2_ln<0,1><<<NN/TM, 256, 0, stream>>>(nb1, pwn + 32768, upd_b2 + l*H,
                                                ln_g + l*H, ln_b + l*H, x, out_af, xb,
                                                pwN + 82944, pwN + 99328, msg_b1 + (l+1)*H,
                                                nb1, nb2);
    else if (l < 3)
      k_upd2_ln<1,1><<<NN/TM, 256, 0, stream>>>(nb1, pwn + 32768, upd_b2 + l*H,
                                                ln_g + l*H, ln_b + l*H, x, out_af, xb,
                                                pwN + 82944, pwN + 99328, msg_b1 + (l+1)*H,
                                                nb1, nb2);
    else
      k_upd2_ln<1,0><<<NN/TM, 256, 0, stream>>>(nb1, pwn + 32768, upd_b2 + l*H,
                                                ln_g + l*H, ln_b + l*H, x, out_af, xb,
                                                packw, packw, msg_b1, nb1, nb2);
  }

  k_af<<<NH/256, 256, 0, stream>>>(out_af, nb1);
  k_ngemm<1,0,1><<<NN/TM, 256, 0, stream>>>(nb1, packn + NG,         ro_b1, nullptr, nb2);
  k_ngemm<0,1,1><<<NN/TM, 256, 0, stream>>>(nb2, packn + NG + 16384, ro_b2, out_ae, nb1);
  k_gscore<<<NN/TM, 256, 0, stream>>>(nb1, packn + NG + 49152, gp_b1, gp_w2, gp_b2, gsc);
  k_ngemm<1,0,1><<<NN/TM, 256, 0, stream>>>(nb1, packn + NG + 32768, pn_b, nullptr, nb2);
  k_start<<<1, 64, 0, stream>>>(batch, startb);
  k_pool<<<NB, 256, 0, stream>>>(startb, gsc, exb, nb2, out_gaf);
}